// Round 13
// baseline (628.808 us; speedup 1.0000x reference)
//
#include <hip/hip_runtime.h>

// out[b, j, k] for k in [0,20): i=k/2, c=k%2, m = j*B + b - i
//   = (m >= 0) ? inputs[m/30, 0, c] * w_c[m%30] : 0
// out[b, j, k] for k in [20,28) = inputs[b, j, k-18]
// Row-major: inputs (B,30,10), out (B,30,28). row = b*30 + j.
//
// Round 13: register-direct, 2 lanes per output row. No LDS transpose, no
// mid-kernel barriers (r12 post-mortem: kernel is latency/serialization
// bound, not throughput bound — xq table cut scattered loads 5.7x for only
// -12us). Row splits at float 14 into two 56B halves; all stores are
// aligned x4/x2. LDS = 240B (w tables) -> 32 waves/CU (was 20).
//  h=0 lane: front cols 0..13   -> x4@0, x4@16, x4@32, x2@48
//  h=1 lane: front cols 14..19 + tail in[2..9] -> x2@56, x4@64, x4@80, x4@96
// Wave's stores jointly cover every byte of 32 contiguous rows -> L2 merges
// to full lines. pack_kernel keeps the 0:2 gather in a 1MB L2-resident buf.

typedef float f32x4 __attribute__((ext_vector_type(4)));
typedef float f32x2 __attribute__((ext_vector_type(2)));

__global__ __launch_bounds__(256) void pack_kernel(const float* __restrict__ inp,
                                                   float2* __restrict__ xc, int B) {
    int q = blockIdx.x * blockDim.x + threadIdx.x;
    if (q < B) {
        const float* p = inp + (size_t)q * 300;
        xc[q] = make_float2(p[0], p[1]);
    }
}

__global__ __launch_bounds__(256) void main_kernel(
    const float* __restrict__ inp,
    const float2* __restrict__ xc,
    const float* __restrict__ w1,
    const float* __restrict__ w2,
    float* __restrict__ out,
    int B, int nrows) {
    __shared__ float w1s[30], w2s[30];
    int t = threadIdx.x;
    if (t < 30) w1s[t] = w1[t];
    else if (t >= 32 && t < 62) w2s[t - 32] = w2[t - 32];
    __syncthreads();

    int pairid = t >> 1;
    int h = t & 1;
    int row = blockIdx.x * 128 + pairid;
    if (row >= nrows) return;

    int b = row / 30;
    int j = row - b * 30;
    int m0 = j * B + b;
    int q0 = m0 / 30;
    int r0 = m0 - q0 * 30;

    float2 xa = xc[q0];
    float2 xb = (q0 >= 1) ? xc[q0 - 1] : make_float2(0.f, 0.f);

    float* orow = out + (size_t)row * 28;

    if (h == 0) {
        float f[14];
#pragma unroll
        for (int k = 0; k < 14; ++k) {
            int i = k >> 1, c = k & 1;
            bool useA = (r0 >= i);
            int r = useA ? (r0 - i) : (r0 - i + 30);
            float x = c ? (useA ? xa.y : xb.y) : (useA ? xa.x : xb.x);
            float w = c ? w2s[r] : w1s[r];
            f[k] = (m0 - i >= 0) ? x * w : 0.f;
        }
        *(f32x4*)(orow + 0)  = (f32x4){f[0], f[1], f[2], f[3]};
        *(f32x4*)(orow + 4)  = (f32x4){f[4], f[5], f[6], f[7]};
        *(f32x4*)(orow + 8)  = (f32x4){f[8], f[9], f[10], f[11]};
        *(f32x2*)(orow + 12) = (f32x2){f[12], f[13]};
    } else {
        // tail loads first (independent, hide latency under the tap math)
        const float* irow = inp + (size_t)row * 10;
        f32x2 a0 = *(const f32x2*)(irow + 2);   // in[2,3]  (8B-aligned)
        f32x2 a1 = *(const f32x2*)(irow + 4);   // in[4,5]
        f32x2 a2 = *(const f32x2*)(irow + 6);   // in[6,7]
        f32x2 a3 = *(const f32x2*)(irow + 8);   // in[8,9]

        float f[6];
#pragma unroll
        for (int k = 14; k < 20; ++k) {
            int i = k >> 1, c = k & 1;
            bool useA = (r0 >= i);
            int r = useA ? (r0 - i) : (r0 - i + 30);
            float x = c ? (useA ? xa.y : xb.y) : (useA ? xa.x : xb.x);
            float w = c ? w2s[r] : w1s[r];
            f[k - 14] = (m0 - i >= 0) ? x * w : 0.f;
        }
        *(f32x2*)(orow + 14) = (f32x2){f[0], f[1]};
        *(f32x4*)(orow + 16) = (f32x4){f[2], f[3], f[4], f[5]};
        *(f32x4*)(orow + 20) = (f32x4){a0.x, a0.y, a1.x, a1.y};
        *(f32x4*)(orow + 24) = (f32x4){a2.x, a2.y, a3.x, a3.y};
    }
}

extern "C" void kernel_launch(void* const* d_in, const int* in_sizes, int n_in,
                              void* d_out, int out_size, void* d_ws, size_t ws_size,
                              hipStream_t stream) {
    const float* inp = (const float*)d_in[0];
    const float* w1  = (const float*)d_in[1];
    const float* w2  = (const float*)d_in[2];
    float* out = (float*)d_out;

    int B = in_sizes[0] / 300;      // inputs is (B, 30, 10)
    int nrows = B * 30;

    float2* xc = (float2*)d_ws;     // B float2s = 1MB

    pack_kernel<<<(B + 255) / 256, 256, 0, stream>>>(inp, xc, B);

    int grid = (nrows + 127) / 128;   // 30720 for B=131072 (exact)
    main_kernel<<<grid, 256, 0, stream>>>(inp, xc, w1, w2, out, B, nrows);
}

// Round 14
// 602.874 us; speedup vs baseline: 1.0430x; 1.0430x over previous
//
#include <hip/hip_runtime.h>

// out[b, j, k] for k in [0,20): i=k/2, c=k%2, m = j*B + b - i
//   = (m >= 0) ? inputs[m/30, 0, c] * w_c[m%30] : 0
// out[b, j, k] for k in [20,28) = inputs[b, j, k-18]
// Row-major: inputs (B,30,10), out (B,30,28). row = b*30 + j.
//
// Round 14: one output float4 per thread. Flat f4 index g = row*7 + c4;
// consecutive lanes -> consecutive f4s -> every wave store is 1KB of
// contiguous full lines (r13 taught: per-instruction store contiguity is
// the dominant effect; r13's 112B-stride stores cost +84us). Values are
// computed in registers: c4<=4 lanes do 4 front taps (q0/r0 divmod + two
// 8B L2-hit loads from the packed xc buffer), c4 in {5,6} lanes copy the
// tail via two float2 loads. No lout LDS (240B w tables only -> 32
// waves/CU), no mid-kernel barriers, no nontemporal stores.

typedef float f32x4 __attribute__((ext_vector_type(4)));
typedef float f32x2 __attribute__((ext_vector_type(2)));

__global__ __launch_bounds__(256) void pack_kernel(const float* __restrict__ inp,
                                                   float2* __restrict__ xc, int B) {
    int q = blockIdx.x * blockDim.x + threadIdx.x;
    if (q < B) {
        const float* p = inp + (size_t)q * 300;
        xc[q] = make_float2(p[0], p[1]);
    }
}

__global__ __launch_bounds__(256) void main_kernel(
    const float* __restrict__ inp,
    const float2* __restrict__ xc,
    const float* __restrict__ w1,
    const float* __restrict__ w2,
    float* __restrict__ out,
    int B, int nG) {                 // nG = nrows * 7 (total output float4s)
    __shared__ float w1s[30], w2s[30];
    int t = threadIdx.x;
    if (t < 30) w1s[t] = w1[t];
    else if (t >= 32 && t < 62) w2s[t - 32] = w2[t - 32];
    __syncthreads();

    int g = blockIdx.x * 256 + t;
    if (g >= nG) return;
    int row = g / 7;                 // compiler emits magic-mul
    int c4 = g - row * 7;

    f32x4 v;
    if (c4 < 5) {
        int b = row / 30;
        int j = row - b * 30;
        int m0 = j * B + b;
        int q0 = m0 / 30;
        int r0 = m0 - q0 * 30;
        float2 xa = xc[q0];                                   // L2-hot 1MB buf
        float2 xb = (q0 >= 1) ? xc[q0 - 1] : make_float2(0.f, 0.f);
#pragma unroll
        for (int e = 0; e < 4; ++e) {
            int k = c4 * 4 + e;      // output col 0..19
            int i = k >> 1, c = k & 1;
            bool useA = (r0 >= i);
            int r = useA ? (r0 - i) : (r0 - i + 30);
            float x = c ? (useA ? xa.y : xb.y) : (useA ? xa.x : xb.x);
            float w = c ? w2s[r] : w1s[r];
            v[e] = (m0 - i >= 0) ? x * w : 0.f;
        }
    } else {
        // cols 20..27 = in[2..9]; 8B-aligned float2 pair (40*row+8+32*(c4-5))
        const float* irow = inp + (size_t)row * 10 + 2 + (c4 - 5) * 4;
        f32x2 lo = *(const f32x2*)(irow);
        f32x2 hi = *(const f32x2*)(irow + 2);
        v = (f32x4){lo.x, lo.y, hi.x, hi.y};
    }
    *(f32x4*)(out + (size_t)g * 4) = v;   // wave: 64 consecutive f4s = 1KB
}

extern "C" void kernel_launch(void* const* d_in, const int* in_sizes, int n_in,
                              void* d_out, int out_size, void* d_ws, size_t ws_size,
                              hipStream_t stream) {
    const float* inp = (const float*)d_in[0];
    const float* w1  = (const float*)d_in[1];
    const float* w2  = (const float*)d_in[2];
    float* out = (float*)d_out;

    int B = in_sizes[0] / 300;       // inputs is (B, 30, 10)
    int nrows = B * 30;
    int nG = nrows * 7;              // 27,525,120 for B=131072

    float2* xc = (float2*)d_ws;      // B float2s = 1MB

    pack_kernel<<<(B + 255) / 256, 256, 0, stream>>>(inp, xc, B);

    int grid = (nG + 255) / 256;     // 107,520 exact
    main_kernel<<<grid, 256, 0, stream>>>(inp, xc, w1, w2, out, B, nG);
}